// Round 4
// baseline (165.498 us; speedup 1.0000x reference)
//
#include <hip/hip_runtime.h>
#include <stdint.h>

typedef unsigned short ushort_t;
typedef __attribute__((ext_vector_type(8))) short short8;
typedef __attribute__((ext_vector_type(4))) float f32x4;
typedef __attribute__((ext_vector_type(16))) float f32x16;
typedef __attribute__((ext_vector_type(4))) uint32_t u32x4;

#define MFMA16 __builtin_amdgcn_mfma_f32_16x16x32_bf16
#define MFMA32 __builtin_amdgcn_mfma_f32_32x32x16_bf16

__device__ inline ushort_t f2bf(float f) {
    union { float f; uint32_t u; } x; x.f = f;
    uint32_t r = x.u + 0x7FFFu + ((x.u >> 16) & 1u);
    return (ushort_t)(r >> 16);
}
__device__ inline uint32_t pack2bf(float lo, float hi) {
    return (uint32_t)f2bf(lo) | ((uint32_t)f2bf(hi) << 16);
}

// ---------------- prep kernels ----------------
__global__ __launch_bounds__(256) void conv_x(const float* __restrict__ x,
                                              ushort_t* __restrict__ xb, int n) {
    int base = (blockIdx.x * 256 + threadIdx.x) * 8;
    if (base >= n) return;
    short8 v;
#pragma unroll
    for (int j = 0; j < 8; j++) v[j] = (short)f2bf(x[base + j]);
    *reinterpret_cast<short8*>(&xb[base]) = v;
}

// Wqkv[3072][512]; q-rows (n%1536 < 512) pre-scaled by 0.125 (attn score scale; exact in bf16)
__global__ __launch_bounds__(256) void prep_wqkv(const float* __restrict__ wl,
                                                 const float* __restrict__ wg,
                                                 const float* __restrict__ bl,
                                                 const float* __restrict__ bg,
                                                 ushort_t* __restrict__ W,
                                                 float* __restrict__ bqkv) {
    int gid = blockIdx.x * 256 + threadIdx.x;
    int base = gid * 8;   // < 3072*512
    short8 v;
#pragma unroll
    for (int j = 0; j < 8; j++) {
        int e = base + j;
        int n = e >> 9;
        int nm = n >= 1536 ? n - 1536 : n;
        float sc = (nm < 512) ? 0.125f : 1.0f;
        float f = (e < 1536 * 512) ? wl[e] : wg[e - 1536 * 512];
        v[j] = (short)f2bf(f * sc);
    }
    *reinterpret_cast<short8*>(&W[base]) = v;
    if (gid < 3072) {
        int nm = gid >= 1536 ? gid - 1536 : gid;
        float sc = (nm < 512) ? 0.125f : 1.0f;
        bqkv[gid] = ((gid < 1536) ? bl[gid] : bg[gid - 1536]) * sc;
    }
}

__global__ __launch_bounds__(256) void prep_w3(const float* __restrict__ wl,
                                               const float* __restrict__ wg,
                                               const float* __restrict__ bl,
                                               const float* __restrict__ bg,
                                               const float* __restrict__ gate,
                                               ushort_t* __restrict__ W,
                                               float* __restrict__ b3) {
    float gv = gate[0];
    int gid = blockIdx.x * 256 + threadIdx.x;
    int base = gid * 8;   // < 512*1024
    short8 v;
#pragma unroll
    for (int j = 0; j < 8; j++) {
        int e = base + j;
        int n = e >> 10, k = e & 1023;
        float f = (k < 512) ? gv * wl[n * 512 + k] : (1.0f - gv) * wg[n * 512 + (k - 512)];
        v[j] = (short)f2bf(f);
    }
    *reinterpret_cast<short8*>(&W[base]) = v;
    if (gid < 512) b3[gid] = gv * bl[gid] + (1.0f - gv) * bg[gid];
}

// ---------------- GEMM: C[M][N] = A[M][K] * B[N][K]^T + bias ----------------
template<int NI, bool OUT_BF16>
__global__ __launch_bounds__(256) void gemm_bt(const ushort_t* __restrict__ A,
                                               const ushort_t* __restrict__ B,
                                               const float* __restrict__ bias,
                                               void* __restrict__ Cout,
                                               int M, int N, int K) {
    constexpr int TN = NI * 32;
    __shared__ ushort_t As[128 * 72];
    __shared__ ushort_t Bs[TN * 72];
    const int tid = threadIdx.x;
    const int lane = tid & 63, wid = tid >> 6;
    const int g = lane >> 4, c = lane & 15;
    const int wm = wid >> 1, wn = wid & 1;
    const int bm = blockIdx.x, bn = blockIdx.y;

    f32x4 acc[4][NI];
#pragma unroll
    for (int i = 0; i < 4; i++)
#pragma unroll
        for (int j = 0; j < NI; j++) acc[i][j] = f32x4{0.f, 0.f, 0.f, 0.f};

    for (int ks = 0; ks < K; ks += 64) {
#pragma unroll
        for (int it = 0; it < 4 + TN / 32; it++) {
            int idx = tid + it * 256;
            if (idx < 1024) {
                int r = idx >> 3, cc = idx & 7;
                *reinterpret_cast<short8*>(&As[r * 72 + cc * 8]) =
                    *reinterpret_cast<const short8*>(&A[(size_t)(bm * 128 + r) * K + ks + cc * 8]);
            } else {
                int j2 = idx - 1024;
                int r = j2 >> 3, cc = j2 & 7;
                *reinterpret_cast<short8*>(&Bs[r * 72 + cc * 8]) =
                    *reinterpret_cast<const short8*>(&B[(size_t)(bn * TN + r) * K + ks + cc * 8]);
            }
        }
        __syncthreads();
#pragma unroll
        for (int kk = 0; kk < 2; kk++) {
            short8 a[4], b[NI];
#pragma unroll
            for (int mi = 0; mi < 4; mi++)
                a[mi] = *reinterpret_cast<const short8*>(&As[(wm * 64 + mi * 16 + c) * 72 + kk * 32 + g * 8]);
#pragma unroll
            for (int ni = 0; ni < NI; ni++)
                b[ni] = *reinterpret_cast<const short8*>(&Bs[(wn * (NI * 16) + ni * 16 + c) * 72 + kk * 32 + g * 8]);
#pragma unroll
            for (int mi = 0; mi < 4; mi++)
#pragma unroll
                for (int ni = 0; ni < NI; ni++)
                    acc[mi][ni] = MFMA16(a[mi], b[ni], acc[mi][ni], 0, 0, 0);
        }
        __syncthreads();
    }
#pragma unroll
    for (int mi = 0; mi < 4; mi++) {
#pragma unroll
        for (int ni = 0; ni < NI; ni++) {
            int n = bn * TN + wn * (NI * 16) + ni * 16 + c;
            float bv = bias[n];
#pragma unroll
            for (int r = 0; r < 4; r++) {
                int m = bm * 128 + wm * 64 + mi * 16 + g * 4 + r;
                float v = acc[mi][ni][r] + bv;
                if (OUT_BF16) ((ushort_t*)Cout)[(size_t)m * N + n] = f2bf(v);
                else          ((float*)Cout)[(size_t)m * N + n] = v;
            }
        }
    }
}

// ---------------- V transpose: VT[branch][bh][d][l] ----------------
__global__ __launch_bounds__(256) void transpose_v(const ushort_t* __restrict__ QKV,
                                                   ushort_t* __restrict__ VT) {
    const int lt = blockIdx.x, bh = blockIdx.y, br = blockIdx.z;
    const int b = bh >> 3, h = bh & 7;
    const int coff = (br ? 1536 : 0) + 1024 + h * 64;
    __shared__ ushort_t T[64][72];
    const int tid = threadIdx.x;
#pragma unroll
    for (int it = 0; it < 2; it++) {
        int idx = tid + it * 256;
        int l = idx >> 3, cc = idx & 7;
        *reinterpret_cast<short8*>(&T[l][cc * 8]) =
            *reinterpret_cast<const short8*>(&QKV[(size_t)(b * 2048 + lt * 64 + l) * 3072 + coff + cc * 8]);
    }
    __syncthreads();
#pragma unroll
    for (int it = 0; it < 2; it++) {
        int idx = tid + it * 256;
        int d = idx >> 3, lc = idx & 7;
        short8 v;
#pragma unroll
        for (int j = 0; j < 8; j++) v[j] = (short)T[lc * 8 + j][d];
        *reinterpret_cast<short8*>(&VT[(size_t)br * 2097152 + (size_t)(bh * 64 + d) * 2048 + lt * 64 + lc * 8]) = v;
    }
}

// ---------------- attention: direct-from-L2, 4-way KV split, LDS merge ----------------
// WG = 4 waves, one (qb32, bh, branch); wave w does kt = kt0+w, +4, ...
// id bits: [2:0]=bh_low (XCD slot), [8:3]=qb, [9]=bh_high, [10]=branch
__global__ __launch_bounds__(256) void attn_direct(const ushort_t* __restrict__ QKV,
                                                   const ushort_t* __restrict__ VT,
                                                   ushort_t* __restrict__ A2) {
    const int id = blockIdx.x;
    const int bh = (id & 7) | (((id >> 9) & 1) << 3);
    const int qb = (id >> 3) & 63;
    const bool LOCAL = ((id >> 10) & 1) != 0;
    const int b = bh >> 3, h = bh & 7;
    const int coff = LOCAL ? 0 : 1536;
    const int aoff = LOCAL ? 0 : 512;

    const int tid = threadIdx.x, lane = tid & 63, w = tid >> 6;
    const int l31 = lane & 31, hi = lane >> 5;

    __shared__ float Ob[4][32][68];
    __shared__ float Mm[4][32];
    __shared__ float Ll[4][32];

    const int qrow = qb * 32 + l31;
    short8 qf[4];
    {
        const ushort_t* qp = QKV + (size_t)(b * 2048 + qrow) * 3072 + coff + h * 64 + hi * 8;
#pragma unroll
        for (int kd = 0; kd < 4; kd++) qf[kd] = *reinterpret_cast<const short8*>(qp + kd * 16);
    }

    f32x16 o0, o1;
#pragma unroll
    for (int i = 0; i < 16; i++) { o0[i] = 0.f; o1[i] = 0.f; }
    float mrow = -1e30f, lrow = 0.f;

    int kt0 = 0, kt1 = 31;
    if (LOCAL) {
        kt0 = (qb >= 4) ? ((qb - 4) >> 1) : 0;
        int t = (qb * 32 + 159) >> 6;
        kt1 = t > 31 ? 31 : t;
    }

    const ushort_t* kgbase = QKV + (size_t)(b * 2048 + l31) * 3072 + coff + 512 + h * 64 + hi * 8;
    const ushort_t* vtbase = VT + (size_t)(LOCAL ? 0 : 1) * 2097152 + (size_t)(bh * 64 + l31) * 2048 + hi * 8;

    for (int kt = kt0 + w; kt <= kt1; kt += 4) {
        const ushort_t* kp = kgbase + (size_t)kt * (64 * 3072);
        const ushort_t* vp = vtbase + kt * 64;
        short8 ka[8], va[8];
#pragma unroll
        for (int kd = 0; kd < 4; kd++) {
            ka[kd]     = *reinterpret_cast<const short8*>(kp + kd * 16);
            ka[4 + kd] = *reinterpret_cast<const short8*>(kp + 32 * 3072 + kd * 16);
            va[kd]     = *reinterpret_cast<const short8*>(vp + kd * 16);
            va[4 + kd] = *reinterpret_cast<const short8*>(vp + 32 * 2048 + kd * 16);
        }

        // QK^T (swapped): lane holds col q=l31, row k=(r&3)+8*(r>>2)+4*hi (+32 for s1)
        f32x16 s0, s1;
#pragma unroll
        for (int i = 0; i < 16; i++) { s0[i] = 0.f; s1[i] = 0.f; }
#pragma unroll
        for (int kd = 0; kd < 4; kd++) {
            s0 = MFMA32(ka[kd], qf[kd], s0, 0, 0, 0);
            s1 = MFMA32(ka[4 + kd], qf[kd], s1, 0, 0, 0);
        }
        if (LOCAL) {
#pragma unroll
            for (int r = 0; r < 16; r++) {
                int k0 = kt * 64 + (r & 3) + 8 * (r >> 2) + 4 * hi;
                int d0 = qrow - k0; d0 = d0 < 0 ? -d0 : d0;
                int d1 = qrow - (k0 + 32); d1 = d1 < 0 ? -d1 : d1;
                if (d0 > 128) s0[r] = -1e30f;
                if (d1 > 128) s1[r] = -1e30f;
            }
        }
        // online softmax with defer-max (THR=8)
        float pmax = -1e30f;
#pragma unroll
        for (int r = 0; r < 16; r++) pmax = fmaxf(pmax, fmaxf(s0[r], s1[r]));
        pmax = fmaxf(pmax, __shfl_xor(pmax, 32));
        if (!__all(pmax <= mrow + 8.f)) {
            float mnew = fmaxf(mrow, pmax);
            float sc = __expf(mrow - mnew);
            lrow *= sc;
#pragma unroll
            for (int r = 0; r < 16; r++) {
                int qo = (r & 3) + 8 * (r >> 2) + 4 * hi;
                float scv = __shfl(sc, qo);
                o0[r] *= scv; o1[r] *= scv;
            }
            mrow = mnew;
        }
        float ps0 = 0.f, ps1 = 0.f;
        uint32_t pk0[8], pk1[8];
#pragma unroll
        for (int i = 0; i < 8; i++) {
            float a0 = __expf(s0[2 * i] - mrow), b0 = __expf(s0[2 * i + 1] - mrow);
            float a1 = __expf(s1[2 * i] - mrow), b1 = __expf(s1[2 * i + 1] - mrow);
            ps0 += a0 + b0; ps1 += a1 + b1;
            pk0[i] = pack2bf(a0, b0);
            pk1[i] = pack2bf(a1, b1);
        }
        float psum = ps0 + ps1;
        psum += __shfl_xor(psum, 32);
        lrow += psum;

        // PV via permlane32_swap P-redistribution
#pragma unroll
        for (int kb = 0; kb < 2; kb++) {
#pragma unroll
            for (int m = 0; m < 2; m++) {
                uint32_t e0 = kb ? pk1[4 * m + 0] : pk0[4 * m + 0];
                uint32_t e1 = kb ? pk1[4 * m + 1] : pk0[4 * m + 1];
                uint32_t e2 = kb ? pk1[4 * m + 2] : pk0[4 * m + 2];
                uint32_t e3 = kb ? pk1[4 * m + 3] : pk0[4 * m + 3];
                auto w02 = __builtin_amdgcn_permlane32_swap(e0, e2, false, false);
                auto w13 = __builtin_amdgcn_permlane32_swap(e1, e3, false, false);
                u32x4 fv;
                fv[0] = w02[0]; fv[1] = w13[0]; fv[2] = w02[1]; fv[3] = w13[1];
                short8 pf = __builtin_bit_cast(short8, fv);
                int km = kb * 2 + m;
                o0 = MFMA32(pf, va[km], o0, 0, 0, 0);
                o1 = MFMA32(pf, va[4 + km], o1, 0, 0, 0);
            }
        }
    }

    // write partials to LDS
#pragma unroll
    for (int r = 0; r < 16; r++) {
        int qo = (r & 3) + 8 * (r >> 2) + 4 * hi;
        Ob[w][qo][l31] = o0[r];
        Ob[w][qo][32 + l31] = o1[r];
    }
    if (lane < 32) { Mm[w][l31] = mrow; Ll[w][l31] = lrow; }
    __syncthreads();

    // merge: wave w handles rows w*8 .. w*8+7
    {
        const int row = w * 8 + (lane >> 3);
        const int cg = lane & 7;
        float m[4], e[4];
        m[0] = Mm[0][row]; m[1] = Mm[1][row]; m[2] = Mm[2][row]; m[3] = Mm[3][row];
        float M = fmaxf(fmaxf(m[0], m[1]), fmaxf(m[2], m[3]));
        float L = 0.f;
#pragma unroll
        for (int p = 0; p < 4; p++) {
            e[p] = __expf(m[p] - M);
            L += Ll[p][row] * e[p];
        }
        float inv = 1.0f / L;
        f32x4 accA = f32x4{0.f, 0.f, 0.f, 0.f}, accB = f32x4{0.f, 0.f, 0.f, 0.f};
#pragma unroll
        for (int p = 0; p < 4; p++) {
            accA += *reinterpret_cast<const f32x4*>(&Ob[p][row][cg * 8]) * e[p];
            accB += *reinterpret_cast<const f32x4*>(&Ob[p][row][cg * 8 + 4]) * e[p];
        }
        u32x4 fv;
        fv[0] = pack2bf(accA[0] * inv, accA[1] * inv);
        fv[1] = pack2bf(accA[2] * inv, accA[3] * inv);
        fv[2] = pack2bf(accB[0] * inv, accB[1] * inv);
        fv[3] = pack2bf(accB[2] * inv, accB[3] * inv);
        *reinterpret_cast<u32x4*>(&A2[(size_t)(b * 2048 + qb * 32 + row) * 1024 + aoff + h * 64 + cg * 8]) = fv;
    }
}

// ---------------- launcher ----------------
extern "C" void kernel_launch(void* const* d_in, const int* in_sizes, int n_in,
                              void* d_out, int out_size, void* d_ws, size_t ws_size,
                              hipStream_t stream) {
    const float* x      = (const float*)d_in[0];
    const float* wl_in  = (const float*)d_in[2];
    const float* bl_in  = (const float*)d_in[3];
    const float* wl_out = (const float*)d_in[4];
    const float* bl_out = (const float*)d_in[5];
    const float* wg_in  = (const float*)d_in[6];
    const float* bg_in  = (const float*)d_in[7];
    const float* wg_out = (const float*)d_in[8];
    const float* bg_out = (const float*)d_in[9];
    const float* gate   = (const float*)d_in[10];

    char* ws = (char*)d_ws;
    ushort_t* xb   = (ushort_t*)ws;  ws += (size_t)4096 * 512 * 2;
    ushort_t* Wqkv = (ushort_t*)ws;  ws += (size_t)3072 * 512 * 2;
    float*    bqkv = (float*)ws;     ws += (size_t)3072 * 4;
    ushort_t* QKV  = (ushort_t*)ws;  ws += (size_t)4096 * 3072 * 2;
    ushort_t* VT   = (ushort_t*)ws;  ws += (size_t)2 * 16 * 64 * 2048 * 2;
    ushort_t* A2   = (ushort_t*)ws;  ws += (size_t)4096 * 1024 * 2;
    ushort_t* W3   = (ushort_t*)ws;  ws += (size_t)512 * 1024 * 2;
    float*    b3   = (float*)ws;     ws += (size_t)512 * 4;

    conv_x<<<1024, 256, 0, stream>>>(x, xb, 4096 * 512);
    prep_wqkv<<<768, 256, 0, stream>>>(wl_in, wg_in, bl_in, bg_in, Wqkv, bqkv);
    prep_w3<<<256, 256, 0, stream>>>(wl_out, wg_out, bl_out, bg_out, gate, W3, b3);

    gemm_bt<4, true><<<dim3(32, 24), 256, 0, stream>>>(xb, Wqkv, bqkv, QKV, 4096, 3072, 512);
    transpose_v<<<dim3(32, 16, 2), 256, 0, stream>>>(QKV, VT);
    attn_direct<<<2048, 256, 0, stream>>>(QKV, VT, A2);
    gemm_bt<2, false><<<dim3(32, 8), 256, 0, stream>>>(A2, W3, b3, d_out, 4096, 512, 1024);
}

// Round 5
// 140.815 us; speedup vs baseline: 1.1753x; 1.1753x over previous
//
#include <hip/hip_runtime.h>
#include <stdint.h>

typedef unsigned short ushort_t;
typedef __attribute__((ext_vector_type(8))) short short8;
typedef __attribute__((ext_vector_type(4))) float f32x4;
typedef __attribute__((ext_vector_type(16))) float f32x16;
typedef __attribute__((ext_vector_type(4))) uint32_t u32x4;

#define MFMA16 __builtin_amdgcn_mfma_f32_16x16x32_bf16
#define MFMA32 __builtin_amdgcn_mfma_f32_32x32x16_bf16

__device__ inline ushort_t f2bf(float f) {
    union { float f; uint32_t u; } x; x.f = f;
    uint32_t r = x.u + 0x7FFFu + ((x.u >> 16) & 1u);
    return (ushort_t)(r >> 16);
}
__device__ inline uint32_t pack2bf(float lo, float hi) {
    return (uint32_t)f2bf(lo) | ((uint32_t)f2bf(hi) << 16);
}

// ---------------- prep kernels ----------------
__global__ __launch_bounds__(256) void conv_x(const float* __restrict__ x,
                                              ushort_t* __restrict__ xb, int n) {
    int base = (blockIdx.x * 256 + threadIdx.x) * 8;
    if (base >= n) return;
    short8 v;
#pragma unroll
    for (int j = 0; j < 8; j++) v[j] = (short)f2bf(x[base + j]);
    *reinterpret_cast<short8*>(&xb[base]) = v;
}

// Wqkv[3072][512]; q-rows pre-scaled by 0.125*log2(e) -> scores in log2 domain
__global__ __launch_bounds__(256) void prep_wqkv(const float* __restrict__ wl,
                                                 const float* __restrict__ wg,
                                                 const float* __restrict__ bl,
                                                 const float* __restrict__ bg,
                                                 ushort_t* __restrict__ W,
                                                 float* __restrict__ bqkv) {
    const float QSC = 0.125f * 1.44269504089f;
    int gid = blockIdx.x * 256 + threadIdx.x;
    int base = gid * 8;   // < 3072*512
    short8 v;
#pragma unroll
    for (int j = 0; j < 8; j++) {
        int e = base + j;
        int n = e >> 9;
        int nm = n >= 1536 ? n - 1536 : n;
        float sc = (nm < 512) ? QSC : 1.0f;
        float f = (e < 1536 * 512) ? wl[e] : wg[e - 1536 * 512];
        v[j] = (short)f2bf(f * sc);
    }
    *reinterpret_cast<short8*>(&W[base]) = v;
    if (gid < 3072) {
        int nm = gid >= 1536 ? gid - 1536 : gid;
        float sc = (nm < 512) ? QSC : 1.0f;
        bqkv[gid] = ((gid < 1536) ? bl[gid] : bg[gid - 1536]) * sc;
    }
}

__global__ __launch_bounds__(256) void prep_w3(const float* __restrict__ wl,
                                               const float* __restrict__ wg,
                                               const float* __restrict__ bl,
                                               const float* __restrict__ bg,
                                               const float* __restrict__ gate,
                                               ushort_t* __restrict__ W,
                                               float* __restrict__ b3) {
    float gv = gate[0];
    int gid = blockIdx.x * 256 + threadIdx.x;
    int base = gid * 8;   // < 512*1024
    short8 v;
#pragma unroll
    for (int j = 0; j < 8; j++) {
        int e = base + j;
        int n = e >> 10, k = e & 1023;
        float f = (k < 512) ? gv * wl[n * 512 + k] : (1.0f - gv) * wg[n * 512 + (k - 512)];
        v[j] = (short)f2bf(f);
    }
    *reinterpret_cast<short8*>(&W[base]) = v;
    if (gid < 512) b3[gid] = gv * bl[gid] + (1.0f - gv) * bg[gid];
}

// ---------------- GEMM: C[M][N] = A[M][K] * B[N][K]^T + bias ----------------
template<int NI, bool OUT_BF16>
__global__ __launch_bounds__(256) void gemm_bt(const ushort_t* __restrict__ A,
                                               const ushort_t* __restrict__ B,
                                               const float* __restrict__ bias,
                                               void* __restrict__ Cout,
                                               int M, int N, int K) {
    constexpr int TN = NI * 32;
    __shared__ ushort_t As[128 * 72];
    __shared__ ushort_t Bs[TN * 72];
    const int tid = threadIdx.x;
    const int lane = tid & 63, wid = tid >> 6;
    const int g = lane >> 4, c = lane & 15;
    const int wm = wid >> 1, wn = wid & 1;
    const int bm = blockIdx.x, bn = blockIdx.y;

    f32x4 acc[4][NI];
#pragma unroll
    for (int i = 0; i < 4; i++)
#pragma unroll
        for (int j = 0; j < NI; j++) acc[i][j] = f32x4{0.f, 0.f, 0.f, 0.f};

    for (int ks = 0; ks < K; ks += 64) {
#pragma unroll
        for (int it = 0; it < 4 + TN / 32; it++) {
            int idx = tid + it * 256;
            if (idx < 1024) {
                int r = idx >> 3, cc = idx & 7;
                *reinterpret_cast<short8*>(&As[r * 72 + cc * 8]) =
                    *reinterpret_cast<const short8*>(&A[(size_t)(bm * 128 + r) * K + ks + cc * 8]);
            } else {
                int j2 = idx - 1024;
                int r = j2 >> 3, cc = j2 & 7;
                *reinterpret_cast<short8*>(&Bs[r * 72 + cc * 8]) =
                    *reinterpret_cast<const short8*>(&B[(size_t)(bn * TN + r) * K + ks + cc * 8]);
            }
        }
        __syncthreads();
#pragma unroll
        for (int kk = 0; kk < 2; kk++) {
            short8 a[4], b[NI];
#pragma unroll
            for (int mi = 0; mi < 4; mi++)
                a[mi] = *reinterpret_cast<const short8*>(&As[(wm * 64 + mi * 16 + c) * 72 + kk * 32 + g * 8]);
#pragma unroll
            for (int ni = 0; ni < NI; ni++)
                b[ni] = *reinterpret_cast<const short8*>(&Bs[(wn * (NI * 16) + ni * 16 + c) * 72 + kk * 32 + g * 8]);
#pragma unroll
            for (int mi = 0; mi < 4; mi++)
#pragma unroll
                for (int ni = 0; ni < NI; ni++)
                    acc[mi][ni] = MFMA16(a[mi], b[ni], acc[mi][ni], 0, 0, 0);
        }
        __syncthreads();
    }
#pragma unroll
    for (int mi = 0; mi < 4; mi++) {
#pragma unroll
        for (int ni = 0; ni < NI; ni++) {
            int n = bn * TN + wn * (NI * 16) + ni * 16 + c;
            float bv = bias[n];
#pragma unroll
            for (int r = 0; r < 4; r++) {
                int m = bm * 128 + wm * 64 + mi * 16 + g * 4 + r;
                float v = acc[mi][ni][r] + bv;
                if (OUT_BF16) ((ushort_t*)Cout)[(size_t)m * N + n] = f2bf(v);
                else          ((float*)Cout)[(size_t)m * N + n] = v;
            }
        }
    }
}

// ---------------- V transpose: VT[branch][bh][d][l] ----------------
__global__ __launch_bounds__(256) void transpose_v(const ushort_t* __restrict__ QKV,
                                                   ushort_t* __restrict__ VT) {
    const int lt = blockIdx.x, bh = blockIdx.y, br = blockIdx.z;
    const int b = bh >> 3, h = bh & 7;
    const int coff = (br ? 1536 : 0) + 1024 + h * 64;
    __shared__ ushort_t T[64][72];
    const int tid = threadIdx.x;
#pragma unroll
    for (int it = 0; it < 2; it++) {
        int idx = tid + it * 256;
        int l = idx >> 3, cc = idx & 7;
        *reinterpret_cast<short8*>(&T[l][cc * 8]) =
            *reinterpret_cast<const short8*>(&QKV[(size_t)(b * 2048 + lt * 64 + l) * 3072 + coff + cc * 8]);
    }
    __syncthreads();
#pragma unroll
    for (int it = 0; it < 2; it++) {
        int idx = tid + it * 256;
        int d = idx >> 3, lc = idx & 7;
        short8 v;
#pragma unroll
        for (int j = 0; j < 8; j++) v[j] = (short)T[lc * 8 + j][d];
        *reinterpret_cast<short8*>(&VT[(size_t)br * 2097152 + (size_t)(bh * 64 + d) * 2048 + lt * 64 + lc * 8]) = v;
    }
}

// ---------------- attention: 128-row Q block, shared K/V LDS, double-buffered ----------------
// WG = 4 waves; wave w owns q-rows [qb*128 + w*32, +32); all waves share kt stream.
// id bits: [2:0]=h (XCD slot), [6:3]=qb (16), [7]=b, [8]=branch (global first)
__global__ __launch_bounds__(256) void attn_shared(const ushort_t* __restrict__ QKV,
                                                   const ushort_t* __restrict__ VT,
                                                   ushort_t* __restrict__ A2) {
    const int gid = blockIdx.x;
    const int h = gid & 7;
    const int qb = (gid >> 3) & 15;
    const int b = (gid >> 7) & 1;
    const bool LOCAL = ((gid >> 8) & 1) != 0;
    const int bh = b * 8 + h;
    const int coff = LOCAL ? 0 : 1536;
    const int aoff = LOCAL ? 0 : 512;

    const int tid = threadIdx.x, lane = tid & 63, w = tid >> 6;
    const int l31 = lane & 31, hi = lane >> 5;

    __shared__ __align__(16) ushort_t Ks[2][64 * 72];
    __shared__ __align__(16) ushort_t Vs[2][64 * 72];

    const int qrow = qb * 128 + w * 32 + l31;
    short8 qf[4];
    {
        const ushort_t* qp = QKV + (size_t)(b * 2048 + qrow) * 3072 + coff + h * 64 + hi * 8;
#pragma unroll
        for (int kd = 0; kd < 4; kd++) qf[kd] = *reinterpret_cast<const short8*>(qp + kd * 16);
    }

    f32x16 o0, o1;
#pragma unroll
    for (int i = 0; i < 16; i++) { o0[i] = 0.f; o1[i] = 0.f; }
    float mrow = -1e30f, lrow = 0.f;

    int kt0 = 0, kt1 = 31;
    if (LOCAL) {
        kt0 = qb >= 1 ? 2 * qb - 2 : 0;
        kt1 = 2 * qb + 3 < 31 ? 2 * qb + 3 : 31;
    }

    // staging: thread t handles rows r0 and r0+32, 16B chunk c0 (ushort offset)
    const int r0 = tid >> 3, c0 = (tid & 7) * 8;
    const ushort_t* Kg = QKV + (size_t)(b * 2048) * 3072 + coff + 512 + h * 64;
    const ushort_t* Vg = VT + (size_t)(LOCAL ? 0 : 1) * 2097152 + (size_t)(bh * 64) * 2048;

    // per-tile compute
    auto tile_step = [&](int cur, int kt) {
        const ushort_t* Kc = &Ks[cur][0];
        const ushort_t* Vc = &Vs[cur][0];
        f32x16 s0, s1;
#pragma unroll
        for (int i = 0; i < 16; i++) { s0[i] = 0.f; s1[i] = 0.f; }
#pragma unroll
        for (int kd = 0; kd < 4; kd++) {
            short8 kf0 = *reinterpret_cast<const short8*>(&Kc[l31 * 72 + kd * 16 + hi * 8]);
            short8 kf1 = *reinterpret_cast<const short8*>(&Kc[(32 + l31) * 72 + kd * 16 + hi * 8]);
            s0 = MFMA32(kf0, qf[kd], s0, 0, 0, 0);
            s1 = MFMA32(kf1, qf[kd], s1, 0, 0, 0);
        }
        if (LOCAL) {
#pragma unroll
            for (int r = 0; r < 16; r++) {
                int k0 = kt * 64 + (r & 3) + 8 * (r >> 2) + 4 * hi;
                int d0 = qrow - k0; d0 = d0 < 0 ? -d0 : d0;
                int d1 = qrow - (k0 + 32); d1 = d1 < 0 ? -d1 : d1;
                if (d0 > 128) s0[r] = -2e30f;
                if (d1 > 128) s1[r] = -2e30f;
            }
        }
        // online softmax, log2 domain, defer-max (THR=8)
        float pmax = -2e30f;
#pragma unroll
        for (int r = 0; r < 16; r++) pmax = fmaxf(pmax, fmaxf(s0[r], s1[r]));
        pmax = fmaxf(pmax, __shfl_xor(pmax, 32));
        if (!__all(pmax <= mrow + 8.f)) {
            float mnew = fmaxf(mrow, pmax);
            float sc = exp2f(mrow - mnew);
            lrow *= sc;
#pragma unroll
            for (int r = 0; r < 16; r++) {
                int qo = (r & 3) + 8 * (r >> 2) + 4 * hi;
                float scv = __shfl(sc, qo);
                o0[r] *= scv; o1[r] *= scv;
            }
            mrow = mnew;
        }
        float ps0 = 0.f, ps1 = 0.f;
        uint32_t pk0[8], pk1[8];
#pragma unroll
        for (int i = 0; i < 8; i++) {
            float a0 = exp2f(s0[2 * i] - mrow), b0 = exp2f(s0[2 * i + 1] - mrow);
            float a1 = exp2f(s1[2 * i] - mrow), b1 = exp2f(s1[2 * i + 1] - mrow);
            ps0 += a0 + b0; ps1 += a1 + b1;
            pk0[i] = pack2bf(a0, b0);
            pk1[i] = pack2bf(a1, b1);
        }
        float psum = ps0 + ps1;
        psum += __shfl_xor(psum, 32);
        lrow += psum;

        // PV via permlane32_swap P-redistribution
#pragma unroll
        for (int kb = 0; kb < 2; kb++) {
#pragma unroll
            for (int m = 0; m < 2; m++) {
                uint32_t e0 = kb ? pk1[4 * m + 0] : pk0[4 * m + 0];
                uint32_t e1 = kb ? pk1[4 * m + 1] : pk0[4 * m + 1];
                uint32_t e2 = kb ? pk1[4 * m + 2] : pk0[4 * m + 2];
                uint32_t e3 = kb ? pk1[4 * m + 3] : pk0[4 * m + 3];
                auto w02 = __builtin_amdgcn_permlane32_swap(e0, e2, false, false);
                auto w13 = __builtin_amdgcn_permlane32_swap(e1, e3, false, false);
                u32x4 fv;
                fv[0] = w02[0]; fv[1] = w13[0]; fv[2] = w02[1]; fv[3] = w13[1];
                short8 pf = __builtin_bit_cast(short8, fv);
                int km = kb * 2 + m;
                short8 vf0 = *reinterpret_cast<const short8*>(&Vc[l31 * 72 + km * 16 + hi * 8]);
                short8 vf1 = *reinterpret_cast<const short8*>(&Vc[(32 + l31) * 72 + km * 16 + hi * 8]);
                o0 = MFMA32(pf, vf0, o0, 0, 0, 0);
                o1 = MFMA32(pf, vf1, o1, 0, 0, 0);
            }
        }
    };

    // prologue: stage kt0 into buffer 0
    {
        const ushort_t* kp = Kg + (size_t)(kt0 * 64) * 3072;
        const ushort_t* vp = Vg + kt0 * 64;
        short8 ka0 = *reinterpret_cast<const short8*>(kp + (size_t)r0 * 3072 + c0);
        short8 ka1 = *reinterpret_cast<const short8*>(kp + (size_t)(r0 + 32) * 3072 + c0);
        short8 va0 = *reinterpret_cast<const short8*>(vp + (size_t)r0 * 2048 + c0);
        short8 va1 = *reinterpret_cast<const short8*>(vp + (size_t)(r0 + 32) * 2048 + c0);
        *reinterpret_cast<short8*>(&Ks[0][r0 * 72 + c0]) = ka0;
        *reinterpret_cast<short8*>(&Ks[0][(r0 + 32) * 72 + c0]) = ka1;
        *reinterpret_cast<short8*>(&Vs[0][r0 * 72 + c0]) = va0;
        *reinterpret_cast<short8*>(&Vs[0][(r0 + 32) * 72 + c0]) = va1;
        __syncthreads();
    }

    int cur = 0;
    for (int kt = kt0; kt < kt1; ++kt) {
        // issue next-tile loads first; they land during compute below
        const ushort_t* kp = Kg + (size_t)((kt + 1) * 64) * 3072;
        const ushort_t* vp = Vg + (kt + 1) * 64;
        short8 ka0 = *reinterpret_cast<const short8*>(kp + (size_t)r0 * 3072 + c0);
        short8 ka1 = *reinterpret_cast<const short8*>(kp + (size_t)(r0 + 32) * 3072 + c0);
        short8 va0 = *reinterpret_cast<const short8*>(vp + (size_t)r0 * 2048 + c0);
        short8 va1 = *reinterpret_cast<const short8*>(vp + (size_t)(r0 + 32) * 2048 + c0);

        tile_step(cur, kt);

        int nxt = cur ^ 1;
        *reinterpret_cast<short8*>(&Ks[nxt][r0 * 72 + c0]) = ka0;
        *reinterpret_cast<short8*>(&Ks[nxt][(r0 + 32) * 72 + c0]) = ka1;
        *reinterpret_cast<short8*>(&Vs[nxt][r0 * 72 + c0]) = va0;
        *reinterpret_cast<short8*>(&Vs[nxt][(r0 + 32) * 72 + c0]) = va1;
        __syncthreads();
        cur = nxt;
    }
    tile_step(cur, kt1);

    // epilogue: direct write, no merge
#pragma unroll
    for (int r = 0; r < 16; r++) {
        int qo = (r & 3) + 8 * (r >> 2) + 4 * hi;
        float lr = __shfl(lrow, qo);
        float inv = 1.0f / lr;
        size_t rowb = (size_t)(b * 2048 + qb * 128 + w * 32 + qo) * 1024 + aoff + h * 64;
        A2[rowb + l31] = f2bf(o0[r] * inv);
        A2[rowb + 32 + l31] = f2bf(o1[r] * inv);
    }
}

// ---------------- launcher ----------------
extern "C" void kernel_launch(void* const* d_in, const int* in_sizes, int n_in,
                              void* d_out, int out_size, void* d_ws, size_t ws_size,
                              hipStream_t stream) {
    const float* x      = (const float*)d_in[0];
    const float* wl_in  = (const float*)d_in[2];
    const float* bl_in  = (const float*)d_in[3];
    const float* wl_out = (const float*)d_in[4];
    const float* bl_out = (const float*)d_in[5];
    const float* wg_in  = (const float*)d_in[6];
    const float* bg_in  = (const float*)d_in[7];
    const float* wg_out = (const float*)d_in[8];
    const float* bg_out = (const float*)d_in[9];
    const float* gate   = (const float*)d_in[10];

    char* ws = (char*)d_ws;
    ushort_t* xb   = (ushort_t*)ws;  ws += (size_t)4096 * 512 * 2;
    ushort_t* Wqkv = (ushort_t*)ws;  ws += (size_t)3072 * 512 * 2;
    float*    bqkv = (float*)ws;     ws += (size_t)3072 * 4;
    ushort_t* QKV  = (ushort_t*)ws;  ws += (size_t)4096 * 3072 * 2;
    ushort_t* VT   = (ushort_t*)ws;  ws += (size_t)2 * 16 * 64 * 2048 * 2;
    ushort_t* A2   = (ushort_t*)ws;  ws += (size_t)4096 * 1024 * 2;
    ushort_t* W3   = (ushort_t*)ws;  ws += (size_t)512 * 1024 * 2;
    float*    b3   = (float*)ws;     ws += (size_t)512 * 4;

    conv_x<<<1024, 256, 0, stream>>>(x, xb, 4096 * 512);
    prep_wqkv<<<768, 256, 0, stream>>>(wl_in, wg_in, bl_in, bg_in, Wqkv, bqkv);
    prep_w3<<<256, 256, 0, stream>>>(wl_out, wg_out, bl_out, bg_out, gate, W3, b3);

    gemm_bt<4, true><<<dim3(32, 24), 256, 0, stream>>>(xb, Wqkv, bqkv, QKV, 4096, 3072, 512);
    transpose_v<<<dim3(32, 16, 2), 256, 0, stream>>>(QKV, VT);
    attn_shared<<<512, 256, 0, stream>>>(QKV, VT, A2);
    gemm_bt<2, false><<<dim3(32, 8), 256, 0, stream>>>(A2, W3, b3, d_out, 4096, 512, 1024);
}

// Round 6
// 127.612 us; speedup vs baseline: 1.2969x; 1.1035x over previous
//
#include <hip/hip_runtime.h>
#include <stdint.h>

typedef unsigned short ushort_t;
typedef __attribute__((ext_vector_type(8))) short short8;
typedef __attribute__((ext_vector_type(4))) float f32x4;
typedef __attribute__((ext_vector_type(16))) float f32x16;
typedef __attribute__((ext_vector_type(4))) uint32_t u32x4;

#define MFMA16 __builtin_amdgcn_mfma_f32_16x16x32_bf16
#define MFMA32 __builtin_amdgcn_mfma_f32_32x32x16_bf16

__device__ inline ushort_t f2bf(float f) {
    union { float f; uint32_t u; } x; x.f = f;
    uint32_t r = x.u + 0x7FFFu + ((x.u >> 16) & 1u);
    return (ushort_t)(r >> 16);
}
__device__ inline uint32_t pack2bf(float lo, float hi) {
    return (uint32_t)f2bf(lo) | ((uint32_t)f2bf(hi) << 16);
}
// single-instruction packed f32->bf16 (RNE), gfx950
__device__ inline uint32_t cvtpk(float lo, float hi) {
    uint32_t r;
    asm("v_cvt_pk_bf16_f32 %0, %1, %2" : "=v"(r) : "v"(lo), "v"(hi));
    return r;
}
#define EXP2R __builtin_amdgcn_exp2f   // raw v_exp_f32

// ---------------- prep kernels ----------------
__global__ __launch_bounds__(256) void conv_x(const float* __restrict__ x,
                                              ushort_t* __restrict__ xb, int n) {
    int base = (blockIdx.x * 256 + threadIdx.x) * 8;
    if (base >= n) return;
    short8 v;
#pragma unroll
    for (int j = 0; j < 8; j++) v[j] = (short)f2bf(x[base + j]);
    *reinterpret_cast<short8*>(&xb[base]) = v;
}

// Wqkv[3072][512]; q-rows pre-scaled by 0.125*log2(e) -> scores in log2 domain
__global__ __launch_bounds__(256) void prep_wqkv(const float* __restrict__ wl,
                                                 const float* __restrict__ wg,
                                                 const float* __restrict__ bl,
                                                 const float* __restrict__ bg,
                                                 ushort_t* __restrict__ W,
                                                 float* __restrict__ bqkv) {
    const float QSC = 0.125f * 1.44269504089f;
    int gid = blockIdx.x * 256 + threadIdx.x;
    int base = gid * 8;   // < 3072*512
    short8 v;
#pragma unroll
    for (int j = 0; j < 8; j++) {
        int e = base + j;
        int n = e >> 9;
        int nm = n >= 1536 ? n - 1536 : n;
        float sc = (nm < 512) ? QSC : 1.0f;
        float f = (e < 1536 * 512) ? wl[e] : wg[e - 1536 * 512];
        v[j] = (short)f2bf(f * sc);
    }
    *reinterpret_cast<short8*>(&W[base]) = v;
    if (gid < 3072) {
        int nm = gid >= 1536 ? gid - 1536 : gid;
        float sc = (nm < 512) ? QSC : 1.0f;
        bqkv[gid] = ((gid < 1536) ? bl[gid] : bg[gid - 1536]) * sc;
    }
}

__global__ __launch_bounds__(256) void prep_w3(const float* __restrict__ wl,
                                               const float* __restrict__ wg,
                                               const float* __restrict__ bl,
                                               const float* __restrict__ bg,
                                               const float* __restrict__ gate,
                                               ushort_t* __restrict__ W,
                                               float* __restrict__ b3) {
    float gv = gate[0];
    int gid = blockIdx.x * 256 + threadIdx.x;
    int base = gid * 8;   // < 512*1024
    short8 v;
#pragma unroll
    for (int j = 0; j < 8; j++) {
        int e = base + j;
        int n = e >> 10, k = e & 1023;
        float f = (k < 512) ? gv * wl[n * 512 + k] : (1.0f - gv) * wg[n * 512 + (k - 512)];
        v[j] = (short)f2bf(f);
    }
    *reinterpret_cast<short8*>(&W[base]) = v;
    if (gid < 512) b3[gid] = gv * bl[gid] + (1.0f - gv) * bg[gid];
}

// ---------------- GEMM: C[M][N] = A[M][K] * B[N][K]^T + bias ----------------
template<int NI, bool OUT_BF16>
__global__ __launch_bounds__(256) void gemm_bt(const ushort_t* __restrict__ A,
                                               const ushort_t* __restrict__ B,
                                               const float* __restrict__ bias,
                                               void* __restrict__ Cout,
                                               int M, int N, int K) {
    constexpr int TN = NI * 32;
    __shared__ ushort_t As[128 * 72];
    __shared__ ushort_t Bs[TN * 72];
    const int tid = threadIdx.x;
    const int lane = tid & 63, wid = tid >> 6;
    const int g = lane >> 4, c = lane & 15;
    const int wm = wid >> 1, wn = wid & 1;
    const int bm = blockIdx.x, bn = blockIdx.y;

    f32x4 acc[4][NI];
#pragma unroll
    for (int i = 0; i < 4; i++)
#pragma unroll
        for (int j = 0; j < NI; j++) acc[i][j] = f32x4{0.f, 0.f, 0.f, 0.f};

    for (int ks = 0; ks < K; ks += 64) {
#pragma unroll
        for (int it = 0; it < 4 + TN / 32; it++) {
            int idx = tid + it * 256;
            if (idx < 1024) {
                int r = idx >> 3, cc = idx & 7;
                *reinterpret_cast<short8*>(&As[r * 72 + cc * 8]) =
                    *reinterpret_cast<const short8*>(&A[(size_t)(bm * 128 + r) * K + ks + cc * 8]);
            } else {
                int j2 = idx - 1024;
                int r = j2 >> 3, cc = j2 & 7;
                *reinterpret_cast<short8*>(&Bs[r * 72 + cc * 8]) =
                    *reinterpret_cast<const short8*>(&B[(size_t)(bn * TN + r) * K + ks + cc * 8]);
            }
        }
        __syncthreads();
#pragma unroll
        for (int kk = 0; kk < 2; kk++) {
            short8 a[4], b[NI];
#pragma unroll
            for (int mi = 0; mi < 4; mi++)
                a[mi] = *reinterpret_cast<const short8*>(&As[(wm * 64 + mi * 16 + c) * 72 + kk * 32 + g * 8]);
#pragma unroll
            for (int ni = 0; ni < NI; ni++)
                b[ni] = *reinterpret_cast<const short8*>(&Bs[(wn * (NI * 16) + ni * 16 + c) * 72 + kk * 32 + g * 8]);
#pragma unroll
            for (int mi = 0; mi < 4; mi++)
#pragma unroll
                for (int ni = 0; ni < NI; ni++)
                    acc[mi][ni] = MFMA16(a[mi], b[ni], acc[mi][ni], 0, 0, 0);
        }
        __syncthreads();
    }
#pragma unroll
    for (int mi = 0; mi < 4; mi++) {
#pragma unroll
        for (int ni = 0; ni < NI; ni++) {
            int n = bn * TN + wn * (NI * 16) + ni * 16 + c;
            float bv = bias[n];
#pragma unroll
            for (int r = 0; r < 4; r++) {
                int m = bm * 128 + wm * 64 + mi * 16 + g * 4 + r;
                float v = acc[mi][ni][r] + bv;
                if (OUT_BF16) ((ushort_t*)Cout)[(size_t)m * N + n] = f2bf(v);
                else          ((float*)Cout)[(size_t)m * N + n] = v;
            }
        }
    }
}

// ---------------- V transpose: VT[branch][bh][d][l] ----------------
__global__ __launch_bounds__(256) void transpose_v(const ushort_t* __restrict__ QKV,
                                                   ushort_t* __restrict__ VT) {
    const int lt = blockIdx.x, bh = blockIdx.y, br = blockIdx.z;
    const int b = bh >> 3, h = bh & 7;
    const int coff = (br ? 1536 : 0) + 1024 + h * 64;
    __shared__ ushort_t T[64][72];
    const int tid = threadIdx.x;
#pragma unroll
    for (int it = 0; it < 2; it++) {
        int idx = tid + it * 256;
        int l = idx >> 3, cc = idx & 7;
        *reinterpret_cast<short8*>(&T[l][cc * 8]) =
            *reinterpret_cast<const short8*>(&QKV[(size_t)(b * 2048 + lt * 64 + l) * 3072 + coff + cc * 8]);
    }
    __syncthreads();
#pragma unroll
    for (int it = 0; it < 2; it++) {
        int idx = tid + it * 256;
        int d = idx >> 3, lc = idx & 7;
        short8 v;
#pragma unroll
        for (int j = 0; j < 8; j++) v[j] = (short)T[lc * 8 + j][d];
        *reinterpret_cast<short8*>(&VT[(size_t)br * 2097152 + (size_t)(bh * 64 + d) * 2048 + lt * 64 + lc * 8]) = v;
    }
}

// ---------------- attention: 128-row Q block, shared K/V LDS, double-buffered ----------------
// WG = 4 waves; wave w owns q-rows [qb*128 + w*32, +32); all waves share kt stream.
// id bits: [2:0]=h (XCD slot), [6:3]=qb (16), [7]=b, [8]=branch (global first)
__global__ __launch_bounds__(256) void attn_shared(const ushort_t* __restrict__ QKV,
                                                   const ushort_t* __restrict__ VT,
                                                   ushort_t* __restrict__ A2) {
    const int gid = blockIdx.x;
    const int h = gid & 7;
    const int qb = (gid >> 3) & 15;
    const int b = (gid >> 7) & 1;
    const bool LOCAL = ((gid >> 8) & 1) != 0;
    const int bh = b * 8 + h;
    const int coff = LOCAL ? 0 : 1536;
    const int aoff = LOCAL ? 0 : 512;

    const int tid = threadIdx.x, lane = tid & 63, w = tid >> 6;
    const int l31 = lane & 31, hi = lane >> 5;

    __shared__ __align__(16) ushort_t Ks[2][64 * 72];
    __shared__ __align__(16) ushort_t Vs[2][64 * 72];

    const int qrow = qb * 128 + w * 32 + l31;
    short8 qf[4];
    {
        const ushort_t* qp = QKV + (size_t)(b * 2048 + qrow) * 3072 + coff + h * 64 + hi * 8;
#pragma unroll
        for (int kd = 0; kd < 4; kd++) qf[kd] = *reinterpret_cast<const short8*>(qp + kd * 16);
    }

    f32x16 o0, o1;
#pragma unroll
    for (int i = 0; i < 16; i++) { o0[i] = 0.f; o1[i] = 0.f; }
    float mrow = -1e30f, lrow = 0.f;

    int kt0 = 0, kt1 = 31;
    if (LOCAL) {
        kt0 = qb >= 1 ? 2 * qb - 2 : 0;
        kt1 = 2 * qb + 3 < 31 ? 2 * qb + 3 : 31;
    }

    // staging: thread t handles rows r0 and r0+32, 16B chunk c0 (ushort offset)
    const int r0 = tid >> 3, c0 = (tid & 7) * 8;
    const ushort_t* Kg = QKV + (size_t)(b * 2048) * 3072 + coff + 512 + h * 64;
    const ushort_t* Vg = VT + (size_t)(LOCAL ? 0 : 1) * 2097152 + (size_t)(bh * 64) * 2048;

    // per-tile compute
    auto tile_step = [&](int cur, int kt) {
        const ushort_t* Kc = &Ks[cur][0];
        const ushort_t* Vc = &Vs[cur][0];
        f32x16 s0, s1;
#pragma unroll
        for (int i = 0; i < 16; i++) { s0[i] = 0.f; s1[i] = 0.f; }
        __builtin_amdgcn_s_setprio(1);
#pragma unroll
        for (int kd = 0; kd < 4; kd++) {
            short8 kf0 = *reinterpret_cast<const short8*>(&Kc[l31 * 72 + kd * 16 + hi * 8]);
            short8 kf1 = *reinterpret_cast<const short8*>(&Kc[(32 + l31) * 72 + kd * 16 + hi * 8]);
            s0 = MFMA32(kf0, qf[kd], s0, 0, 0, 0);
            s1 = MFMA32(kf1, qf[kd], s1, 0, 0, 0);
        }
        __builtin_amdgcn_s_setprio(0);
        if (LOCAL) {
#pragma unroll
            for (int r = 0; r < 16; r++) {
                int k0 = kt * 64 + (r & 3) + 8 * (r >> 2) + 4 * hi;
                int d0 = qrow - k0; d0 = d0 < 0 ? -d0 : d0;
                int d1 = qrow - (k0 + 32); d1 = d1 < 0 ? -d1 : d1;
                if (d0 > 128) s0[r] = -2e30f;
                if (d1 > 128) s1[r] = -2e30f;
            }
        }
        // online softmax, log2 domain, defer-max (THR=8)
        float pmax = -2e30f;
#pragma unroll
        for (int r = 0; r < 16; r++) pmax = fmaxf(pmax, fmaxf(s0[r], s1[r]));
        pmax = fmaxf(pmax, __shfl_xor(pmax, 32));
        if (!__all(pmax <= mrow + 8.f)) {
            float mnew = fmaxf(mrow, pmax);
            float sc = EXP2R(mrow - mnew);
            lrow *= sc;
#pragma unroll
            for (int r = 0; r < 16; r++) {
                int qo = (r & 3) + 8 * (r >> 2) + 4 * hi;
                float scv = __shfl(sc, qo);
                o0[r] *= scv; o1[r] *= scv;
            }
            mrow = mnew;
        }
        float ps0 = 0.f, ps1 = 0.f;
        uint32_t pk0[8], pk1[8];
#pragma unroll
        for (int i = 0; i < 8; i++) {
            float a0 = EXP2R(s0[2 * i] - mrow), b0 = EXP2R(s0[2 * i + 1] - mrow);
            float a1 = EXP2R(s1[2 * i] - mrow), b1 = EXP2R(s1[2 * i + 1] - mrow);
            ps0 += a0 + b0; ps1 += a1 + b1;
            pk0[i] = cvtpk(a0, b0);
            pk1[i] = cvtpk(a1, b1);
        }
        float psum = ps0 + ps1;
        psum += __shfl_xor(psum, 32);
        lrow += psum;

        // PV via permlane32_swap P-redistribution
        __builtin_amdgcn_s_setprio(1);
#pragma unroll
        for (int kb = 0; kb < 2; kb++) {
#pragma unroll
            for (int m = 0; m < 2; m++) {
                uint32_t e0 = kb ? pk1[4 * m + 0] : pk0[4 * m + 0];
                uint32_t e1 = kb ? pk1[4 * m + 1] : pk0[4 * m + 1];
                uint32_t e2 = kb ? pk1[4 * m + 2] : pk0[4 * m + 2];
                uint32_t e3 = kb ? pk1[4 * m + 3] : pk0[4 * m + 3];
                auto w02 = __builtin_amdgcn_permlane32_swap(e0, e2, false, false);
                auto w13 = __builtin_amdgcn_permlane32_swap(e1, e3, false, false);
                u32x4 fv;
                fv[0] = w02[0]; fv[1] = w13[0]; fv[2] = w02[1]; fv[3] = w13[1];
                short8 pf = __builtin_bit_cast(short8, fv);
                int km = kb * 2 + m;
                short8 vf0 = *reinterpret_cast<const short8*>(&Vc[l31 * 72 + km * 16 + hi * 8]);
                short8 vf1 = *reinterpret_cast<const short8*>(&Vc[(32 + l31) * 72 + km * 16 + hi * 8]);
                o0 = MFMA32(pf, vf0, o0, 0, 0, 0);
                o1 = MFMA32(pf, vf1, o1, 0, 0, 0);
            }
        }
        __builtin_amdgcn_s_setprio(0);
    };

    // prologue: stage kt0 into buffer 0
    {
        const ushort_t* kp = Kg + (size_t)(kt0 * 64) * 3072;
        const ushort_t* vp = Vg + kt0 * 64;
        short8 ka0 = *reinterpret_cast<const short8*>(kp + (size_t)r0 * 3072 + c0);
        short8 ka1 = *reinterpret_cast<const short8*>(kp + (size_t)(r0 + 32) * 3072 + c0);
        short8 va0 = *reinterpret_cast<const short8*>(vp + (size_t)r0 * 2048 + c0);
        short8 va1 = *reinterpret_cast<const short8*>(vp + (size_t)(r0 + 32) * 2048 + c0);
        *reinterpret_cast<short8*>(&Ks[0][r0 * 72 + c0]) = ka0;
        *reinterpret_cast<short8*>(&Ks[0][(r0 + 32) * 72 + c0]) = ka1;
        *reinterpret_cast<short8*>(&Vs[0][r0 * 72 + c0]) = va0;
        *reinterpret_cast<short8*>(&Vs[0][(r0 + 32) * 72 + c0]) = va1;
        __syncthreads();
    }

    int cur = 0;
    for (int kt = kt0; kt < kt1; ++kt) {
        // issue next-tile loads first; they land during compute below
        const ushort_t* kp = Kg + (size_t)((kt + 1) * 64) * 3072;
        const ushort_t* vp = Vg + (kt + 1) * 64;
        short8 ka0 = *reinterpret_cast<const short8*>(kp + (size_t)r0 * 3072 + c0);
        short8 ka1 = *reinterpret_cast<const short8*>(kp + (size_t)(r0 + 32) * 3072 + c0);
        short8 va0 = *reinterpret_cast<const short8*>(vp + (size_t)r0 * 2048 + c0);
        short8 va1 = *reinterpret_cast<const short8*>(vp + (size_t)(r0 + 32) * 2048 + c0);

        tile_step(cur, kt);

        int nxt = cur ^ 1;
        *reinterpret_cast<short8*>(&Ks[nxt][r0 * 72 + c0]) = ka0;
        *reinterpret_cast<short8*>(&Ks[nxt][(r0 + 32) * 72 + c0]) = ka1;
        *reinterpret_cast<short8*>(&Vs[nxt][r0 * 72 + c0]) = va0;
        *reinterpret_cast<short8*>(&Vs[nxt][(r0 + 32) * 72 + c0]) = va1;
        __syncthreads();
        cur = nxt;
    }
    tile_step(cur, kt1);

    // epilogue: direct write, no merge
#pragma unroll
    for (int r = 0; r < 16; r++) {
        int qo = (r & 3) + 8 * (r >> 2) + 4 * hi;
        float lr = __shfl(lrow, qo);
        float inv = 1.0f / lr;
        size_t rowb = (size_t)(b * 2048 + qb * 128 + w * 32 + qo) * 1024 + aoff + h * 64;
        A2[rowb + l31] = f2bf(o0[r] * inv);
        A2[rowb + 32 + l31] = f2bf(o1[r] * inv);
    }
}

// ---------------- launcher ----------------
extern "C" void kernel_launch(void* const* d_in, const int* in_sizes, int n_in,
                              void* d_out, int out_size, void* d_ws, size_t ws_size,
                              hipStream_t stream) {
    const float* x      = (const float*)d_in[0];
    const float* wl_in  = (const float*)d_in[2];
    const float* bl_in  = (const float*)d_in[3];
    const float* wl_out = (const float*)d_in[4];
    const float* bl_out = (const float*)d_in[5];
    const float* wg_in  = (const float*)d_in[6];
    const float* bg_in  = (const float*)d_in[7];
    const float* wg_out = (const float*)d_in[8];
    const float* bg_out = (const float*)d_in[9];
    const float* gate   = (const float*)d_in[10];

    char* ws = (char*)d_ws;
    ushort_t* xb   = (ushort_t*)ws;  ws += (size_t)4096 * 512 * 2;
    ushort_t* Wqkv = (ushort_t*)ws;  ws += (size_t)3072 * 512 * 2;
    float*    bqkv = (float*)ws;     ws += (size_t)3072 * 4;
    ushort_t* QKV  = (ushort_t*)ws;  ws += (size_t)4096 * 3072 * 2;
    ushort_t* VT   = (ushort_t*)ws;  ws += (size_t)2 * 16 * 64 * 2048 * 2;
    ushort_t* A2   = (ushort_t*)ws;  ws += (size_t)4096 * 1024 * 2;
    ushort_t* W3   = (ushort_t*)ws;  ws += (size_t)512 * 1024 * 2;
    float*    b3   = (float*)ws;     ws += (size_t)512 * 4;

    conv_x<<<1024, 256, 0, stream>>>(x, xb, 4096 * 512);
    prep_wqkv<<<768, 256, 0, stream>>>(wl_in, wg_in, bl_in, bg_in, Wqkv, bqkv);
    prep_w3<<<256, 256, 0, stream>>>(wl_out, wg_out, bl_out, bg_out, gate, W3, b3);

    gemm_bt<4, true><<<dim3(32, 24), 256, 0, stream>>>(xb, Wqkv, bqkv, QKV, 4096, 3072, 512);
    transpose_v<<<dim3(32, 16, 2), 256, 0, stream>>>(QKV, VT);
    attn_shared<<<512, 256, 0, stream>>>(QKV, VT, A2);
    gemm_bt<2, false><<<dim3(32, 8), 256, 0, stream>>>(A2, W3, b3, d_out, 4096, 512, 1024);
}